// Round 1
// baseline (471.380 us; speedup 1.0000x reference)
//
#include <hip/hip_runtime.h>
#include <math.h>

#define ALPHA 5e-4f
#define BIG 1e30f

// ---------------- Kernel A: row squared norms of X ----------------
__global__ void rownorm_kernel(const float* __restrict__ X, float* __restrict__ sqn,
                               int n, int d) {
    int wave = threadIdx.x >> 6;          // 4 waves per block
    int lane = threadIdx.x & 63;
    int row = blockIdx.x * 4 + wave;
    if (row >= n) return;
    const float* xr = X + (size_t)row * d;
    float s = 0.f;
    for (int c = lane * 4; c < d; c += 64 * 4) {
        float4 v = *reinterpret_cast<const float4*>(xr + c);
        s += v.x * v.x + v.y * v.y + v.z * v.z + v.w * v.w;
    }
    for (int off = 1; off < 64; off <<= 1)
        s += __shfl_xor(s, off, 64);
    if (lane == 0) sqn[row] = s;
}

// ---------------- Kernel B: fp32 gram tiles + in-tile per-row top-2 ----------------
// Tile 128x128, BK=16, 256 threads, each thread 8x8 outputs.
// Candidate value s = sqn[col] - 2*dot(x_row, x_col)  (monotone in d^2 for fixed row).
#define BM 128
#define BN 128
#define BK 16

__global__ __launch_bounds__(256)
void gram_top2_kernel(const float* __restrict__ X, const float* __restrict__ sqn,
                      float* __restrict__ cand_s, int* __restrict__ cand_i,
                      int n, int d, int ncb) {
    __shared__ float As[BK][BM];
    __shared__ float Bs[BK][BN];
    const int cb = blockIdx.x, rb = blockIdx.y;
    const int row0 = rb * BM, col0 = cb * BN;
    const int tid = threadIdx.x;
    const int tx = tid & 15, ty = tid >> 4;

    float acc[8][8];
#pragma unroll
    for (int i = 0; i < 8; ++i)
#pragma unroll
        for (int j = 0; j < 8; ++j) acc[i][j] = 0.f;

    const int lrow = tid >> 1;            // 0..127
    const int lcol = (tid & 1) * 8;       // 0 or 8
    const float* Aptr = X + (size_t)(row0 + lrow) * d + lcol;
    const float* Bptr = X + (size_t)(col0 + lrow) * d + lcol;

    for (int k0 = 0; k0 < d; k0 += BK) {
        float4 a0 = *reinterpret_cast<const float4*>(Aptr + k0);
        float4 a1 = *reinterpret_cast<const float4*>(Aptr + k0 + 4);
        float4 b0 = *reinterpret_cast<const float4*>(Bptr + k0);
        float4 b1 = *reinterpret_cast<const float4*>(Bptr + k0 + 4);
        __syncthreads();                  // protect prior iteration's reads
        As[lcol + 0][lrow] = a0.x; As[lcol + 1][lrow] = a0.y;
        As[lcol + 2][lrow] = a0.z; As[lcol + 3][lrow] = a0.w;
        As[lcol + 4][lrow] = a1.x; As[lcol + 5][lrow] = a1.y;
        As[lcol + 6][lrow] = a1.z; As[lcol + 7][lrow] = a1.w;
        Bs[lcol + 0][lrow] = b0.x; Bs[lcol + 1][lrow] = b0.y;
        Bs[lcol + 2][lrow] = b0.z; Bs[lcol + 3][lrow] = b0.w;
        Bs[lcol + 4][lrow] = b1.x; Bs[lcol + 5][lrow] = b1.y;
        Bs[lcol + 6][lrow] = b1.z; Bs[lcol + 7][lrow] = b1.w;
        __syncthreads();
#pragma unroll
        for (int k = 0; k < BK; ++k) {
            float4 av0 = *reinterpret_cast<const float4*>(&As[k][ty * 8]);
            float4 av1 = *reinterpret_cast<const float4*>(&As[k][ty * 8 + 4]);
            float4 bv0 = *reinterpret_cast<const float4*>(&Bs[k][tx * 8]);
            float4 bv1 = *reinterpret_cast<const float4*>(&Bs[k][tx * 8 + 4]);
            float a[8] = {av0.x, av0.y, av0.z, av0.w, av1.x, av1.y, av1.z, av1.w};
            float b[8] = {bv0.x, bv0.y, bv0.z, bv0.w, bv1.x, bv1.y, bv1.z, bv1.w};
#pragma unroll
            for (int i = 0; i < 8; ++i)
#pragma unroll
                for (int j = 0; j < 8; ++j)
                    acc[i][j] = fmaf(a[i], b[j], acc[i][j]);
        }
    }

    // per-row top-2 within this tile
#pragma unroll
    for (int i = 0; i < 8; ++i) {
        const int grow = row0 + ty * 8 + i;
        float s1 = BIG, s2 = BIG;
        int i1 = -1, i2 = -1;
#pragma unroll
        for (int j = 0; j < 8; ++j) {
            const int gcol = col0 + tx * 8 + j;
            float s = sqn[gcol] - 2.f * acc[i][j];
            if (gcol == grow) s = BIG;    // exclude self
            if (s < s1) { s2 = s1; i2 = i1; s1 = s; i1 = gcol; }
            else if (s < s2) { s2 = s; i2 = gcol; }
        }
        // merge across the 16 lanes covering this row (disjoint xor-butterfly)
        for (int off = 1; off < 16; off <<= 1) {
            float b1 = __shfl_xor(s1, off, 16);
            int  bi1 = __shfl_xor(i1, off, 16);
            float b2 = __shfl_xor(s2, off, 16);
            int  bi2 = __shfl_xor(i2, off, 16);
            if (b1 < s1) { s2 = s1; i2 = i1; s1 = b1; i1 = bi1; }
            else if (b1 < s2) { s2 = b1; i2 = bi1; }
            if (b2 < s2) { s2 = b2; i2 = bi2; }
        }
        if (tx == 0) {
            size_t base = ((size_t)grow * ncb + cb) * 2;
            cand_s[base] = s1; cand_s[base + 1] = s2;
            cand_i[base] = i1; cand_i[base + 1] = i2;
        }
    }
}

// ---------------- Kernel C: merge candidates per row + edge terms ----------------
__global__ __launch_bounds__(128)
void merge_edges_kernel(const float* __restrict__ sqn,
                        const float* __restrict__ cand_s, const int* __restrict__ cand_i,
                        const int* __restrict__ yb, const float* __restrict__ yo,
                        float* __restrict__ out, int n, int ncls, int ncb) {
    const int row = blockIdx.x;
    const int tid = threadIdx.x;
    __shared__ int shj[2];
    __shared__ float shw[2];
    __shared__ float red[2][2];

    if (tid < 64) {
        const int total = ncb * 2;        // 64 for n=4096
        float s1 = BIG, s2 = BIG;
        int i1 = -1, i2 = -1;
        if (tid < total) {
            s1 = cand_s[(size_t)row * total + tid];
            i1 = cand_i[(size_t)row * total + tid];
        }
        for (int off = 1; off < 64; off <<= 1) {
            float b1 = __shfl_xor(s1, off, 64);
            int  bi1 = __shfl_xor(i1, off, 64);
            float b2 = __shfl_xor(s2, off, 64);
            int  bi2 = __shfl_xor(i2, off, 64);
            if (b1 < s1) { s2 = s1; i2 = i1; s1 = b1; i1 = bi1; }
            else if (b1 < s2) { s2 = b1; i2 = bi1; }
            if (b2 < s2) { s2 = b2; i2 = bi2; }
        }
        if (tid == 0) {
            const int yr = yb[row];
            float sv[2] = {s1, s2};
            int   jv[2] = {i1, i2};
            for (int k = 0; k < 2; ++k) {
                float d2 = fmaxf(sqn[row] + sv[k], 0.f);
                float dist = sqrtf(d2);
                float sgn = (yr == yb[jv[k]]) ? 1.f : -1.f;
                shj[k] = jv[k];
                shw[k] = sgn * expf(-dist);
            }
        }
    }
    __syncthreads();

    const int j1 = shj[0], j2 = shj[1];
    const float* yr = yo + (size_t)row * ncls;
    const float* y1 = yo + (size_t)j1 * ncls;
    const float* y2 = yo + (size_t)j2 * ncls;
    float a1 = 0.f, a2 = 0.f;
    for (int c = tid; c < ncls; c += 128) {
        float v = yr[c];
        float t1 = v - y1[c];
        float t2 = v - y2[c];
        a1 = fmaf(t1, t1, a1);
        a2 = fmaf(t2, t2, a2);
    }
    for (int off = 1; off < 64; off <<= 1) {
        a1 += __shfl_xor(a1, off, 64);
        a2 += __shfl_xor(a2, off, 64);
    }
    if ((tid & 63) == 0) { red[tid >> 6][0] = a1; red[tid >> 6][1] = a2; }
    __syncthreads();
    if (tid == 0) {
        float n1 = red[0][0] + red[1][0];
        float n2 = red[0][1] + red[1][1];
        float term = shw[0] * sqrtf(n1) + shw[1] * sqrtf(n2);
        atomicAdd(out, ALPHA * term);
    }
}

extern "C" void kernel_launch(void* const* d_in, const int* in_sizes, int n_in,
                              void* d_out, int out_size, void* d_ws, size_t ws_size,
                              hipStream_t stream) {
    const float* X  = (const float*)d_in[0];
    const int*   yb = (const int*)d_in[1];
    const float* yo = (const float*)d_in[2];
    float* out = (float*)d_out;

    const int n    = in_sizes[1];
    const int d    = in_sizes[0] / n;      // 1024
    const int ncls = in_sizes[2] / n;      // 1000
    const int ncb  = n / BN;               // 32

    // workspace layout
    char* wsb = (char*)d_ws;
    size_t off = 0;
    float* sqn = (float*)(wsb + off); off += ((size_t)n * 4 + 255) & ~(size_t)255;
    float* cand_s = (float*)(wsb + off); off += ((size_t)n * ncb * 2 * 4 + 255) & ~(size_t)255;
    int*   cand_i = (int*)(wsb + off);

    hipMemsetAsync(d_out, 0, sizeof(float), stream);

    rownorm_kernel<<<(n + 3) / 4, 256, 0, stream>>>(X, sqn, n, d);

    dim3 grid(n / BN, n / BM);
    gram_top2_kernel<<<grid, 256, 0, stream>>>(X, sqn, cand_s, cand_i, n, d, ncb);

    merge_edges_kernel<<<n, 128, 0, stream>>>(sqn, cand_s, cand_i, yb, yo, out, n, ncls, ncb);
}

// Round 2
// 146.063 us; speedup vs baseline: 3.2272x; 3.2272x over previous
//
#include <hip/hip_runtime.h>
#include <math.h>

#define ALPHA 5e-4f
#define BIG 1e30f

typedef __attribute__((ext_vector_type(8))) short bf16x8;
typedef __attribute__((ext_vector_type(4))) float f32x4;

__device__ __forceinline__ unsigned short f2bf(float x) {
    unsigned u = __builtin_bit_cast(unsigned, x);
    unsigned r = (u + 0x7FFFu + ((u >> 16) & 1u)) >> 16;
    return (unsigned short)r;
}
__device__ __forceinline__ float bf2f(unsigned short b) {
    unsigned u = ((unsigned)b) << 16;
    return __builtin_bit_cast(float, u);
}

__device__ __forceinline__ void gload16(const short* g, short* l) {
    __builtin_amdgcn_global_load_lds(
        (const __attribute__((address_space(1))) void*)g,
        (__attribute__((address_space(3))) void*)l, 16, 0, 0);
}

// ---------------- Kernel A: f32 -> bf16 convert + row squared norms ----------------
// One block per row, 256 threads, 4 floats/thread (d=1024).
__global__ __launch_bounds__(256)
void conv_rownorm_kernel(const float* __restrict__ X, short* __restrict__ Xb,
                         float* __restrict__ sqn, int d) {
    const int row = blockIdx.x;
    const int t = threadIdx.x;
    const int w = t >> 6, lane = t & 63;
    __shared__ float red[4];

    float4 v = reinterpret_cast<const float4*>(X + (size_t)row * d)[t];
    unsigned short b0 = f2bf(v.x), b1 = f2bf(v.y), b2 = f2bf(v.z), b3 = f2bf(v.w);
    float x0 = bf2f(b0), x1 = bf2f(b1), x2 = bf2f(b2), x3 = bf2f(b3);
    float s = x0 * x0 + x1 * x1 + x2 * x2 + x3 * x3;

    short4 sv = make_short4((short)b0, (short)b1, (short)b2, (short)b3);
    *reinterpret_cast<short4*>(Xb + (size_t)row * d + t * 4) = sv;

    for (int off = 1; off < 64; off <<= 1) s += __shfl_xor(s, off, 64);
    if (lane == 0) red[w] = s;
    __syncthreads();
    if (t == 0) sqn[row] = red[0] + red[1] + red[2] + red[3];
}

// ---------------- Kernel B: bf16 MFMA gram + fused per-row top-2 ----------------
// 128x128 tile, BK=32, 256 threads = 4 waves (2x2), each wave 64x64 (4x4 frags
// of 16x16x32). Candidate value s = sqn[col] - 2*dot (monotone in d^2 per row).
// Each wave emits per-row top-2 for its 64-col strip: nsb = n/64 strips.
#define BM 128
#define BN 128
#define BK 32

__global__ __launch_bounds__(256)
void gram_top2_mfma(const short* __restrict__ Xb, const float* __restrict__ sqn,
                    float* __restrict__ cand_s, int* __restrict__ cand_i,
                    int n, int d, int nsb) {
    __shared__ short As[BM * BK];
    __shared__ short Bs[BN * BK];
    const int cb = blockIdx.x, rb = blockIdx.y;
    const int row0 = rb * BM, col0 = cb * BN;
    const int t = threadIdx.x;
    const int w = t >> 6, l = t & 63;
    const int wr = w >> 1, wc = w & 1;
    const int lc = l & 15, lg = l >> 4;

    f32x4 acc[4][4];
#pragma unroll
    for (int i = 0; i < 4; ++i)
#pragma unroll
        for (int j = 0; j < 4; ++j) acc[i][j] = (f32x4){0.f, 0.f, 0.f, 0.f};

    // staging: thread t loads 8 bf16 (16 B); LDS linear [row][BK] row-major.
    // instr p covers rows [p*64, p*64+64).  LDS dest = wave-uniform base + lane*16.
    const size_t gA0 = (size_t)(row0 + (t >> 2)) * d + (t & 3) * 8;
    const size_t gB0 = (size_t)(col0 + (t >> 2)) * d + (t & 3) * 8;
    short* ldsA = As + w * 512;   // bytes: w*1024
    short* ldsB = Bs + w * 512;
    const size_t rstep = (size_t)64 * d;

    for (int k0 = 0; k0 < d; k0 += BK) {
        gload16(Xb + gA0 + k0, ldsA);
        gload16(Xb + gA0 + k0 + rstep, ldsA + 2048);
        gload16(Xb + gB0 + k0, ldsB);
        gload16(Xb + gB0 + k0 + rstep, ldsB + 2048);
        __syncthreads();   // drains vmcnt: tiles visible to all waves

        bf16x8 a[4], b[4];
#pragma unroll
        for (int mi = 0; mi < 4; ++mi)
            a[mi] = *reinterpret_cast<const bf16x8*>(&As[(wr * 64 + mi * 16 + lc) * BK + lg * 8]);
#pragma unroll
        for (int ni = 0; ni < 4; ++ni)
            b[ni] = *reinterpret_cast<const bf16x8*>(&Bs[(wc * 64 + ni * 16 + lc) * BK + lg * 8]);
#pragma unroll
        for (int mi = 0; mi < 4; ++mi)
#pragma unroll
            for (int ni = 0; ni < 4; ++ni)
                acc[mi][ni] = __builtin_amdgcn_mfma_f32_16x16x32_bf16(
                    a[mi], b[ni], acc[mi][ni], 0, 0, 0);
        __syncthreads();   // all reads done before next stage overwrites
    }

    // ---- fused top-2 epilogue ----
    // C frag layout: col = lane&15, row = (lane>>4)*4 + reg.
    float sq_c[4];
#pragma unroll
    for (int ni = 0; ni < 4; ++ni) sq_c[ni] = sqn[col0 + wc * 64 + ni * 16 + lc];
    const int strip = cb * 2 + wc;

#pragma unroll
    for (int mi = 0; mi < 4; ++mi) {
#pragma unroll
        for (int j = 0; j < 4; ++j) {
            const int grow = row0 + wr * 64 + mi * 16 + lg * 4 + j;
            float s1 = BIG, s2 = BIG;
            int i1 = -1, i2 = -1;
#pragma unroll
            for (int ni = 0; ni < 4; ++ni) {
                const int gcol = col0 + wc * 64 + ni * 16 + lc;
                float s = sq_c[ni] - 2.f * acc[mi][ni][j];
                if (gcol == grow) s = BIG;   // exclude self
                if (s < s1) { s2 = s1; i2 = i1; s1 = s; i1 = gcol; }
                else if (s < s2) { s2 = s; i2 = gcol; }
            }
            // merge across the 16 lanes (same lg group) holding this row
            for (int off = 1; off < 16; off <<= 1) {
                float b1 = __shfl_xor(s1, off, 16);
                int  bi1 = __shfl_xor(i1, off, 16);
                float b2 = __shfl_xor(s2, off, 16);
                int  bi2 = __shfl_xor(i2, off, 16);
                if (b1 < s1) { s2 = s1; i2 = i1; s1 = b1; i1 = bi1; }
                else if (b1 < s2) { s2 = b1; i2 = bi1; }
                if (b2 < s2) { s2 = b2; i2 = bi2; }
            }
            if (lc == 0) {
                size_t base = ((size_t)grow * nsb + strip) * 2;
                cand_s[base] = s1; cand_s[base + 1] = s2;
                cand_i[base] = i1; cand_i[base + 1] = i2;
            }
        }
    }
}

// ---------------- Kernel C: merge candidates per row + edge terms ----------------
// 128 candidates per row (nsb=64 strips x 2).
__global__ __launch_bounds__(128)
void merge_edges_kernel(const float* __restrict__ sqn,
                        const float* __restrict__ cand_s, const int* __restrict__ cand_i,
                        const int* __restrict__ yb, const float* __restrict__ yo,
                        float* __restrict__ out, int n, int ncls, int nsb) {
    const int row = blockIdx.x;
    const int tid = threadIdx.x;
    __shared__ float sh_s[2][2];
    __shared__ int   sh_i[2][2];
    __shared__ int shj[2];
    __shared__ float shw[2];
    __shared__ float red[2][2];

    const int total = nsb * 2;            // 128
    float s1 = BIG, s2 = BIG;
    int i1 = -1, i2 = -1;
    if (tid < total) {
        s1 = cand_s[(size_t)row * total + tid];
        i1 = cand_i[(size_t)row * total + tid];
    }
    for (int off = 1; off < 64; off <<= 1) {
        float b1 = __shfl_xor(s1, off, 64);
        int  bi1 = __shfl_xor(i1, off, 64);
        float b2 = __shfl_xor(s2, off, 64);
        int  bi2 = __shfl_xor(i2, off, 64);
        if (b1 < s1) { s2 = s1; i2 = i1; s1 = b1; i1 = bi1; }
        else if (b1 < s2) { s2 = b1; i2 = bi1; }
        if (b2 < s2) { s2 = b2; i2 = bi2; }
    }
    if ((tid & 63) == 0) {
        sh_s[tid >> 6][0] = s1; sh_s[tid >> 6][1] = s2;
        sh_i[tid >> 6][0] = i1; sh_i[tid >> 6][1] = i2;
    }
    __syncthreads();
    if (tid == 0) {
        float a1 = sh_s[0][0], a2 = sh_s[0][1];
        int  ia1 = sh_i[0][0], ia2 = sh_i[0][1];
        float c1 = sh_s[1][0], c2 = sh_s[1][1];
        int  ic1 = sh_i[1][0], ic2 = sh_i[1][1];
        if (c1 < a1) { a2 = a1; ia2 = ia1; a1 = c1; ia1 = ic1; }
        else if (c1 < a2) { a2 = c1; ia2 = ic1; }
        if (c2 < a2) { a2 = c2; ia2 = ic2; }

        const int yr = yb[row];
        float svv[2] = {a1, a2};
        int   jvv[2] = {ia1, ia2};
        for (int k = 0; k < 2; ++k) {
            float d2 = fmaxf(sqn[row] + svv[k], 0.f);
            float dist = sqrtf(d2);
            float sgn = (yr == yb[jvv[k]]) ? 1.f : -1.f;
            shj[k] = jvv[k];
            shw[k] = sgn * expf(-dist);
        }
    }
    __syncthreads();

    const int j1 = shj[0], j2 = shj[1];
    const float* yr = yo + (size_t)row * ncls;
    const float* y1 = yo + (size_t)j1 * ncls;
    const float* y2 = yo + (size_t)j2 * ncls;
    float a1 = 0.f, a2 = 0.f;
    for (int c = tid; c < ncls; c += 128) {
        float v = yr[c];
        float t1 = v - y1[c];
        float t2 = v - y2[c];
        a1 = fmaf(t1, t1, a1);
        a2 = fmaf(t2, t2, a2);
    }
    for (int off = 1; off < 64; off <<= 1) {
        a1 += __shfl_xor(a1, off, 64);
        a2 += __shfl_xor(a2, off, 64);
    }
    if ((tid & 63) == 0) { red[tid >> 6][0] = a1; red[tid >> 6][1] = a2; }
    __syncthreads();
    if (tid == 0) {
        float n1 = red[0][0] + red[1][0];
        float n2 = red[0][1] + red[1][1];
        float term = shw[0] * sqrtf(n1) + shw[1] * sqrtf(n2);
        atomicAdd(out, ALPHA * term);
    }
}

extern "C" void kernel_launch(void* const* d_in, const int* in_sizes, int n_in,
                              void* d_out, int out_size, void* d_ws, size_t ws_size,
                              hipStream_t stream) {
    const float* X  = (const float*)d_in[0];
    const int*   yb = (const int*)d_in[1];
    const float* yo = (const float*)d_in[2];
    float* out = (float*)d_out;

    const int n    = in_sizes[1];          // 4096
    const int d    = in_sizes[0] / n;      // 1024
    const int ncls = in_sizes[2] / n;      // 1000
    const int nsb  = n / 64;               // 64 column strips

    // workspace layout: sqn | Xb (bf16) | cand_s | cand_i
    char* wsb = (char*)d_ws;
    size_t off = 0;
    float* sqn = (float*)(wsb + off);   off += ((size_t)n * 4 + 255) & ~(size_t)255;
    short* Xb  = (short*)(wsb + off);   off += ((size_t)n * d * 2 + 255) & ~(size_t)255;
    float* cand_s = (float*)(wsb + off); off += ((size_t)n * nsb * 2 * 4 + 255) & ~(size_t)255;
    int*   cand_i = (int*)(wsb + off);

    hipMemsetAsync(d_out, 0, sizeof(float), stream);

    conv_rownorm_kernel<<<n, 256, 0, stream>>>(X, Xb, sqn, d);

    dim3 grid(n / BN, n / BM);
    gram_top2_mfma<<<grid, 256, 0, stream>>>(Xb, sqn, cand_s, cand_i, n, d, nsb);

    merge_edges_kernel<<<n, 128, 0, stream>>>(sqn, cand_s, cand_i, yb, yo, out, n, ncls, nsb);
}

// Round 3
// 116.232 us; speedup vs baseline: 4.0555x; 1.2567x over previous
//
#include <hip/hip_runtime.h>
#include <math.h>

#define ALPHA 5e-4f
#define BIG 1e30f

typedef __attribute__((ext_vector_type(8))) short bf16x8;
typedef __attribute__((ext_vector_type(4))) float f32x4;

__device__ __forceinline__ unsigned short f2bf(float x) {
    unsigned u = __builtin_bit_cast(unsigned, x);
    unsigned r = (u + 0x7FFFu + ((u >> 16) & 1u)) >> 16;
    return (unsigned short)r;
}
__device__ __forceinline__ float bf2f(unsigned short b) {
    unsigned u = ((unsigned)b) << 16;
    return __builtin_bit_cast(float, u);
}

__device__ __forceinline__ void gload16(const short* g, short* l) {
    __builtin_amdgcn_global_load_lds(
        (const __attribute__((address_space(1))) void*)g,
        (__attribute__((address_space(3))) void*)l, 16, 0, 0);
}

// ---------------- Kernel A: f32 -> bf16 convert + row squared norms ----------------
// One wave per row, 4 waves/block, barrier-free.
__global__ __launch_bounds__(256)
void conv_rownorm_kernel(const float* __restrict__ X, short* __restrict__ Xb,
                         float* __restrict__ sqn, int d) {
    const int w = threadIdx.x >> 6, lane = threadIdx.x & 63;
    const int row = blockIdx.x * 4 + w;
    const float4* src = reinterpret_cast<const float4*>(X + (size_t)row * d);
    short4* dst = reinterpret_cast<short4*>(Xb + (size_t)row * d);
    float s = 0.f;
    const int nv = d >> 2;
    for (int c = lane; c < nv; c += 64) {
        float4 v = src[c];
        unsigned short b0 = f2bf(v.x), b1 = f2bf(v.y), b2 = f2bf(v.z), b3 = f2bf(v.w);
        float x0 = bf2f(b0), x1 = bf2f(b1), x2 = bf2f(b2), x3 = bf2f(b3);
        s += x0 * x0 + x1 * x1 + x2 * x2 + x3 * x3;
        dst[c] = make_short4((short)b0, (short)b1, (short)b2, (short)b3);
    }
    for (int off = 1; off < 64; off <<= 1) s += __shfl_xor(s, off, 64);
    if (lane == 0) sqn[row] = s;
}

// ---------------- Kernel B: bf16 MFMA gram, upper triangle, fused top-2 ----------------
// 128x128 tile, BK=32, 4 waves (2x2), double-buffered LDS, 2-phase prefetch.
// Row path: per-row top-2 of the wave's 64-col strip  -> strips cb*2+wc.
// Col path (off-diag only): per-col top-2 of the wave's 64-row strip -> strips rb*2+wr.
#define BM 128
#define BN 128
#define BK 32

__global__ __launch_bounds__(256)
void gram_top2_mfma(const short* __restrict__ Xb, const float* __restrict__ sqn,
                    float* __restrict__ cand_s, int* __restrict__ cand_i,
                    int n, int d, int nb) {
    __shared__ short As[2][BM * BK];
    __shared__ short Bs[2][BN * BK];

    // triangular block mapping: idx -> (rb, cb), rb <= cb
    int rb = 0, rem = blockIdx.x;
    while (rem >= nb - rb) { rem -= nb - rb; ++rb; }
    const int cb = rb + rem;

    const int row0 = rb * BM, col0 = cb * BN;
    const int t = threadIdx.x;
    const int w = t >> 6, l = t & 63;
    const int wr = w >> 1, wc = w & 1;
    const int lc = l & 15, lg = l >> 4;

    f32x4 acc[4][4];
#pragma unroll
    for (int i = 0; i < 4; ++i)
#pragma unroll
        for (int j = 0; j < 4; ++j) acc[i][j] = (f32x4){0.f, 0.f, 0.f, 0.f};

    const size_t gA0 = (size_t)(row0 + (t >> 2)) * d + (t & 3) * 8;
    const size_t gB0 = (size_t)(col0 + (t >> 2)) * d + (t & 3) * 8;
    const size_t rstep = (size_t)64 * d;

    // prologue stage
    {
        short* la = As[0] + w * 512;
        short* lb = Bs[0] + w * 512;
        gload16(Xb + gA0, la);
        gload16(Xb + gA0 + rstep, la + 2048);
        gload16(Xb + gB0, lb);
        gload16(Xb + gB0 + rstep, lb + 2048);
    }
    __syncthreads();

    int cur = 0;
    for (int k0 = 0; k0 < d; k0 += BK) {
        if (k0 + BK < d) {
            short* la = As[cur ^ 1] + w * 512;
            short* lb = Bs[cur ^ 1] + w * 512;
            gload16(Xb + gA0 + k0 + BK, la);
            gload16(Xb + gA0 + k0 + BK + rstep, la + 2048);
            gload16(Xb + gB0 + k0 + BK, lb);
            gload16(Xb + gB0 + k0 + BK + rstep, lb + 2048);
        }
        bf16x8 a[4], b[4];
#pragma unroll
        for (int mi = 0; mi < 4; ++mi)
            a[mi] = *reinterpret_cast<const bf16x8*>(&As[cur][(wr * 64 + mi * 16 + lc) * BK + lg * 8]);
#pragma unroll
        for (int ni = 0; ni < 4; ++ni)
            b[ni] = *reinterpret_cast<const bf16x8*>(&Bs[cur][(wc * 64 + ni * 16 + lc) * BK + lg * 8]);
#pragma unroll
        for (int mi = 0; mi < 4; ++mi)
#pragma unroll
            for (int ni = 0; ni < 4; ++ni)
                acc[mi][ni] = __builtin_amdgcn_mfma_f32_16x16x32_bf16(
                    a[mi], b[ni], acc[mi][ni], 0, 0, 0);
        __syncthreads();   // drains vmcnt (next-stage loads) + protects dbuf reuse
        cur ^= 1;
    }

    // ---- row-path epilogue: per-row top-2 over this wave's 64-col strip ----
    // C frag layout: col = lane&15, row = (lane>>4)*4 + reg.
    float sq_c[4];
#pragma unroll
    for (int ni = 0; ni < 4; ++ni) sq_c[ni] = sqn[col0 + wc * 64 + ni * 16 + lc];
    const int strip_r = cb * 2 + wc;

#pragma unroll
    for (int mi = 0; mi < 4; ++mi) {
#pragma unroll
        for (int j = 0; j < 4; ++j) {
            const int grow = row0 + wr * 64 + mi * 16 + lg * 4 + j;
            float s1 = BIG, s2 = BIG;
            int i1 = -1, i2 = -1;
#pragma unroll
            for (int ni = 0; ni < 4; ++ni) {
                const int gcol = col0 + wc * 64 + ni * 16 + lc;
                float s = sq_c[ni] - 2.f * acc[mi][ni][j];
                if (gcol == grow) s = BIG;   // exclude self (diag blocks)
                if (s < s1) { s2 = s1; i2 = i1; s1 = s; i1 = gcol; }
                else if (s < s2) { s2 = s; i2 = gcol; }
            }
            for (int off = 1; off < 16; off <<= 1) {
                float b1 = __shfl_xor(s1, off, 16);
                int  bi1 = __shfl_xor(i1, off, 16);
                float b2 = __shfl_xor(s2, off, 16);
                int  bi2 = __shfl_xor(i2, off, 16);
                if (b1 < s1) { s2 = s1; i2 = i1; s1 = b1; i1 = bi1; }
                else if (b1 < s2) { s2 = b1; i2 = bi1; }
                if (b2 < s2) { s2 = b2; i2 = bi2; }
            }
            if (lc == 0) {
                size_t base = ((size_t)grow * 64 + strip_r) * 2;
                cand_s[base] = s1; cand_s[base + 1] = s2;
                cand_i[base] = i1; cand_i[base + 1] = i2;
            }
        }
    }

    // ---- col-path epilogue (off-diagonal blocks): per-col top-2 over 64 rows ----
    if (rb != cb) {
        float sq_r[4][4];
#pragma unroll
        for (int mi = 0; mi < 4; ++mi)
#pragma unroll
            for (int j = 0; j < 4; ++j)
                sq_r[mi][j] = sqn[row0 + wr * 64 + mi * 16 + lg * 4 + j];
        const int strip_c = rb * 2 + wr;

#pragma unroll
        for (int ni = 0; ni < 4; ++ni) {
            const int gcol = col0 + wc * 64 + ni * 16 + lc;
            float s1 = BIG, s2 = BIG;
            int i1 = -1, i2 = -1;
#pragma unroll
            for (int mi = 0; mi < 4; ++mi)
#pragma unroll
                for (int j = 0; j < 4; ++j) {
                    const int grow = row0 + wr * 64 + mi * 16 + lg * 4 + j;
                    float s = sq_r[mi][j] - 2.f * acc[mi][ni][j];
                    if (s < s1) { s2 = s1; i2 = i1; s1 = s; i1 = grow; }
                    else if (s < s2) { s2 = s; i2 = grow; }
                }
            // merge across lg groups (lanes differing in bits 4,5)
#pragma unroll
            for (int off = 16; off < 64; off <<= 1) {
                float b1 = __shfl_xor(s1, off, 64);
                int  bi1 = __shfl_xor(i1, off, 64);
                float b2 = __shfl_xor(s2, off, 64);
                int  bi2 = __shfl_xor(i2, off, 64);
                if (b1 < s1) { s2 = s1; i2 = i1; s1 = b1; i1 = bi1; }
                else if (b1 < s2) { s2 = b1; i2 = bi1; }
                if (b2 < s2) { s2 = b2; i2 = bi2; }
            }
            if (lg == 0) {
                size_t base = ((size_t)gcol * 64 + strip_c) * 2;
                cand_s[base] = s1; cand_s[base + 1] = s2;
                cand_i[base] = i1; cand_i[base + 1] = i2;
            }
        }
    }
}

// ---------------- Kernel C: merge 128 candidates/row + edge terms ----------------
// One wave per row, barrier-free.
__global__ __launch_bounds__(256)
void merge_edges_kernel(const float* __restrict__ sqn,
                        const float* __restrict__ cand_s, const int* __restrict__ cand_i,
                        const int* __restrict__ yb, const float* __restrict__ yo,
                        float* __restrict__ out, int ncls) {
    const int w = threadIdx.x >> 6, lane = threadIdx.x & 63;
    const int row = blockIdx.x * 4 + w;

    float2 cs = reinterpret_cast<const float2*>(cand_s + (size_t)row * 128)[lane];
    int2   ci = reinterpret_cast<const int2*>(cand_i + (size_t)row * 128)[lane];
    float s1 = cs.x, s2 = cs.y;
    int i1 = ci.x, i2 = ci.y;
    if (s2 < s1) { float ts = s1; s1 = s2; s2 = ts; int ti = i1; i1 = i2; i2 = ti; }

    for (int off = 1; off < 64; off <<= 1) {
        float b1 = __shfl_xor(s1, off, 64);
        int  bi1 = __shfl_xor(i1, off, 64);
        float b2 = __shfl_xor(s2, off, 64);
        int  bi2 = __shfl_xor(i2, off, 64);
        if (b1 < s1) { s2 = s1; i2 = i1; s1 = b1; i1 = bi1; }
        else if (b1 < s2) { s2 = b1; i2 = bi1; }
        if (b2 < s2) { s2 = b2; i2 = bi2; }
    }
    // all lanes converge to the same top-2
    const int yr = yb[row];
    const float sr = sqn[row];
    float w1 = ((yr == yb[i1]) ? 1.f : -1.f) * expf(-sqrtf(fmaxf(sr + s1, 0.f)));
    float w2 = ((yr == yb[i2]) ? 1.f : -1.f) * expf(-sqrtf(fmaxf(sr + s2, 0.f)));

    const float* yrp = yo + (size_t)row * ncls;
    const float* y1p = yo + (size_t)i1 * ncls;
    const float* y2p = yo + (size_t)i2 * ncls;
    float a1 = 0.f, a2 = 0.f;
    for (int c = lane; c < ncls; c += 64) {
        float v = yrp[c];
        float t1 = v - y1p[c];
        float t2 = v - y2p[c];
        a1 = fmaf(t1, t1, a1);
        a2 = fmaf(t2, t2, a2);
    }
    for (int off = 1; off < 64; off <<= 1) {
        a1 += __shfl_xor(a1, off, 64);
        a2 += __shfl_xor(a2, off, 64);
    }
    if (lane == 0)
        atomicAdd(out, ALPHA * (w1 * sqrtf(a1) + w2 * sqrtf(a2)));
}

extern "C" void kernel_launch(void* const* d_in, const int* in_sizes, int n_in,
                              void* d_out, int out_size, void* d_ws, size_t ws_size,
                              hipStream_t stream) {
    const float* X  = (const float*)d_in[0];
    const int*   yb = (const int*)d_in[1];
    const float* yo = (const float*)d_in[2];
    float* out = (float*)d_out;

    const int n    = in_sizes[1];          // 4096
    const int d    = in_sizes[0] / n;      // 1024
    const int ncls = in_sizes[2] / n;      // 1000
    const int nb   = n / BM;               // 32 row/col blocks; 64 strips

    // workspace: sqn | Xb (bf16) | cand_s | cand_i
    char* wsb = (char*)d_ws;
    size_t off = 0;
    float* sqn = (float*)(wsb + off);    off += ((size_t)n * 4 + 255) & ~(size_t)255;
    short* Xb  = (short*)(wsb + off);    off += ((size_t)n * d * 2 + 255) & ~(size_t)255;
    float* cand_s = (float*)(wsb + off); off += ((size_t)n * 64 * 2 * 4 + 255) & ~(size_t)255;
    int*   cand_i = (int*)(wsb + off);

    hipMemsetAsync(d_out, 0, sizeof(float), stream);

    conv_rownorm_kernel<<<n / 4, 256, 0, stream>>>(X, Xb, sqn, d);

    const int ntri = nb * (nb + 1) / 2;    // 528
    gram_top2_mfma<<<ntri, 256, 0, stream>>>(Xb, sqn, cand_s, cand_i, n, d, nb);

    merge_edges_kernel<<<n / 4, 256, 0, stream>>>(sqn, cand_s, cand_i, yb, yo, out, ncls);
}

// Round 4
// 60.805 us; speedup vs baseline: 7.7524x; 1.9116x over previous
//
#include <hip/hip_runtime.h>
#include <math.h>

#define ALPHA 5e-4f
#define BIG 1e30f

typedef __attribute__((ext_vector_type(8))) short bf16x8;
typedef __attribute__((ext_vector_type(4))) float f32x4;

__device__ __forceinline__ unsigned short f2bf(float x) {
    unsigned u = __builtin_bit_cast(unsigned, x);
    unsigned r = (u + 0x7FFFu + ((u >> 16) & 1u)) >> 16;
    return (unsigned short)r;
}
__device__ __forceinline__ float bf2f(unsigned short b) {
    unsigned u = ((unsigned)b) << 16;
    return __builtin_bit_cast(float, u);
}

__device__ __forceinline__ void gload16(const short* g, short* l) {
    __builtin_amdgcn_global_load_lds(
        (const __attribute__((address_space(1))) void*)g,
        (__attribute__((address_space(3))) void*)l, 16, 0, 0);
}

// ---------------- Kernel A: f32 -> bf16 convert + row squared norms ----------------
// One wave per row, 4 waves/block, barrier-free.
__global__ __launch_bounds__(256)
void conv_rownorm_kernel(const float* __restrict__ X, short* __restrict__ Xb,
                         float* __restrict__ sqn, int d) {
    const int w = threadIdx.x >> 6, lane = threadIdx.x & 63;
    const int row = blockIdx.x * 4 + w;
    const float4* src = reinterpret_cast<const float4*>(X + (size_t)row * d);
    short4* dst = reinterpret_cast<short4*>(Xb + (size_t)row * d);
    float s = 0.f;
    const int nv = d >> 2;
    for (int c = lane; c < nv; c += 64) {
        float4 v = src[c];
        unsigned short b0 = f2bf(v.x), b1 = f2bf(v.y), b2 = f2bf(v.z), b3 = f2bf(v.w);
        float x0 = bf2f(b0), x1 = bf2f(b1), x2 = bf2f(b2), x3 = bf2f(b3);
        s += x0 * x0 + x1 * x1 + x2 * x2 + x3 * x3;
        dst[c] = make_short4((short)b0, (short)b1, (short)b2, (short)b3);
    }
    for (int off = 1; off < 64; off <<= 1) s += __shfl_xor(s, off, 64);
    if (lane == 0) sqn[row] = s;
}

// ---------------- Kernel B: bf16 MFMA gram, upper triangle, fused top-2 ----------------
// 128x128 tile, BK=32, 4 waves (2x2), double-buffered LDS, 2-phase prefetch.
// LDS swizzle (T2, both-sides): LDS slot (row, chunk c) holds global 16B-chunk
// c ^ ((row>>1)&3).  Staging: linear LDS dest, pre-swizzled global source.
// Reads: fragment (row, lg) at LDS chunk lg ^ ((row>>1)&3) -> 2-way banks (free).
#define BM 128
#define BN 128
#define BK 32

__global__ __launch_bounds__(256)
void gram_top2_mfma(const short* __restrict__ Xb, const float* __restrict__ sqn,
                    float* __restrict__ cand_s, int* __restrict__ cand_i,
                    int n, int d, int nb) {
    __shared__ short As[2][BM * BK];
    __shared__ short Bs[2][BN * BK];

    // triangular block mapping: idx -> (rb, cb), rb <= cb
    int rb = 0, rem = blockIdx.x;
    while (rem >= nb - rb) { rem -= nb - rb; ++rb; }
    const int cb = rb + rem;

    const int row0 = rb * BM, col0 = cb * BN;
    const int t = threadIdx.x;
    const int w = t >> 6, l = t & 63;
    const int wr = w >> 1, wc = w & 1;
    const int lc = l & 15, lg = l >> 4;

    f32x4 acc[4][4];
#pragma unroll
    for (int i = 0; i < 4; ++i)
#pragma unroll
        for (int j = 0; j < 4; ++j) acc[i][j] = (f32x4){0.f, 0.f, 0.f, 0.f};

    // source chunk swizzle: slot chunk (t&3) wants global chunk (t&3)^((row>>1)&3),
    // and (row>>1)&3 == ((t>>3)&3) for row = t>>2.
    const int gchunk = (t & 3) ^ ((t >> 3) & 3);
    const size_t gA0 = (size_t)(row0 + (t >> 2)) * d + gchunk * 8;
    const size_t gB0 = (size_t)(col0 + (t >> 2)) * d + gchunk * 8;
    const size_t rstep = (size_t)64 * d;

    // read-side swizzled chunk offset (shorts): same for A and B fragments
    const int kswz = (lg ^ ((lc >> 1) & 3)) * 8;

    // prologue stage
    {
        short* la = As[0] + w * 512;
        short* lb = Bs[0] + w * 512;
        gload16(Xb + gA0, la);
        gload16(Xb + gA0 + rstep, la + 2048);
        gload16(Xb + gB0, lb);
        gload16(Xb + gB0 + rstep, lb + 2048);
    }
    __syncthreads();

    int cur = 0;
    for (int k0 = 0; k0 < d; k0 += BK) {
        if (k0 + BK < d) {
            short* la = As[cur ^ 1] + w * 512;
            short* lb = Bs[cur ^ 1] + w * 512;
            gload16(Xb + gA0 + k0 + BK, la);
            gload16(Xb + gA0 + k0 + BK + rstep, la + 2048);
            gload16(Xb + gB0 + k0 + BK, lb);
            gload16(Xb + gB0 + k0 + BK + rstep, lb + 2048);
        }
        bf16x8 a[4], b[4];
#pragma unroll
        for (int mi = 0; mi < 4; ++mi)
            a[mi] = *reinterpret_cast<const bf16x8*>(&As[cur][(wr * 64 + mi * 16 + lc) * BK + kswz]);
#pragma unroll
        for (int ni = 0; ni < 4; ++ni)
            b[ni] = *reinterpret_cast<const bf16x8*>(&Bs[cur][(wc * 64 + ni * 16 + lc) * BK + kswz]);
#pragma unroll
        for (int mi = 0; mi < 4; ++mi)
#pragma unroll
            for (int ni = 0; ni < 4; ++ni)
                acc[mi][ni] = __builtin_amdgcn_mfma_f32_16x16x32_bf16(
                    a[mi], b[ni], acc[mi][ni], 0, 0, 0);
        __syncthreads();   // drains vmcnt (next-stage loads) + protects dbuf reuse
        cur ^= 1;
    }

    // ---- row-path epilogue: per-row top-2 over this wave's 64-col strip ----
    // C frag layout: col = lane&15, row = (lane>>4)*4 + reg.
    float sq_c[4];
#pragma unroll
    for (int ni = 0; ni < 4; ++ni) sq_c[ni] = sqn[col0 + wc * 64 + ni * 16 + lc];
    const int strip_r = cb * 2 + wc;

#pragma unroll
    for (int mi = 0; mi < 4; ++mi) {
#pragma unroll
        for (int j = 0; j < 4; ++j) {
            const int grow = row0 + wr * 64 + mi * 16 + lg * 4 + j;
            float s1 = BIG, s2 = BIG;
            int i1 = -1, i2 = -1;
#pragma unroll
            for (int ni = 0; ni < 4; ++ni) {
                const int gcol = col0 + wc * 64 + ni * 16 + lc;
                float s = sq_c[ni] - 2.f * acc[mi][ni][j];
                if (gcol == grow) s = BIG;   // exclude self (diag blocks)
                if (s < s1) { s2 = s1; i2 = i1; s1 = s; i1 = gcol; }
                else if (s < s2) { s2 = s; i2 = gcol; }
            }
            for (int off = 1; off < 16; off <<= 1) {
                float b1 = __shfl_xor(s1, off, 16);
                int  bi1 = __shfl_xor(i1, off, 16);
                float b2 = __shfl_xor(s2, off, 16);
                int  bi2 = __shfl_xor(i2, off, 16);
                if (b1 < s1) { s2 = s1; i2 = i1; s1 = b1; i1 = bi1; }
                else if (b1 < s2) { s2 = b1; i2 = bi1; }
                if (b2 < s2) { s2 = b2; i2 = bi2; }
            }
            if (lc == 0) {
                size_t base = ((size_t)grow * 64 + strip_r) * 2;
                cand_s[base] = s1; cand_s[base + 1] = s2;
                cand_i[base] = i1; cand_i[base + 1] = i2;
            }
        }
    }

    // ---- col-path epilogue (off-diagonal blocks): per-col top-2 over 64 rows ----
    if (rb != cb) {
        float sq_r[4][4];
#pragma unroll
        for (int mi = 0; mi < 4; ++mi)
#pragma unroll
            for (int j = 0; j < 4; ++j)
                sq_r[mi][j] = sqn[row0 + wr * 64 + mi * 16 + lg * 4 + j];
        const int strip_c = rb * 2 + wr;

#pragma unroll
        for (int ni = 0; ni < 4; ++ni) {
            const int gcol = col0 + wc * 64 + ni * 16 + lc;
            float s1 = BIG, s2 = BIG;
            int i1 = -1, i2 = -1;
#pragma unroll
            for (int mi = 0; mi < 4; ++mi)
#pragma unroll
                for (int j = 0; j < 4; ++j) {
                    const int grow = row0 + wr * 64 + mi * 16 + lg * 4 + j;
                    float s = sq_r[mi][j] - 2.f * acc[mi][ni][j];
                    if (s < s1) { s2 = s1; i2 = i1; s1 = s; i1 = grow; }
                    else if (s < s2) { s2 = s; i2 = grow; }
                }
            // merge across lg groups (lanes differing in bits 4,5)
#pragma unroll
            for (int off = 16; off < 64; off <<= 1) {
                float b1 = __shfl_xor(s1, off, 64);
                int  bi1 = __shfl_xor(i1, off, 64);
                float b2 = __shfl_xor(s2, off, 64);
                int  bi2 = __shfl_xor(i2, off, 64);
                if (b1 < s1) { s2 = s1; i2 = i1; s1 = b1; i1 = bi1; }
                else if (b1 < s2) { s2 = b1; i2 = bi1; }
                if (b2 < s2) { s2 = b2; i2 = bi2; }
            }
            if (lg == 0) {
                size_t base = ((size_t)gcol * 64 + strip_c) * 2;
                cand_s[base] = s1; cand_s[base + 1] = s2;
                cand_i[base] = i1; cand_i[base + 1] = i2;
            }
        }
    }
}

// ---------------- Kernel C: merge 128 candidates/row + edge terms ----------------
// One wave per row, barrier-free, no global atomics: writes partial[row].
__global__ __launch_bounds__(256)
void merge_edges_kernel(const float* __restrict__ sqn,
                        const float* __restrict__ cand_s, const int* __restrict__ cand_i,
                        const int* __restrict__ yb, const float* __restrict__ yo,
                        float* __restrict__ partial, int ncls) {
    const int w = threadIdx.x >> 6, lane = threadIdx.x & 63;
    const int row = blockIdx.x * 4 + w;

    float2 cs = reinterpret_cast<const float2*>(cand_s + (size_t)row * 128)[lane];
    int2   ci = reinterpret_cast<const int2*>(cand_i + (size_t)row * 128)[lane];
    float s1 = cs.x, s2 = cs.y;
    int i1 = ci.x, i2 = ci.y;
    if (s2 < s1) { float ts = s1; s1 = s2; s2 = ts; int ti = i1; i1 = i2; i2 = ti; }

    for (int off = 1; off < 64; off <<= 1) {
        float b1 = __shfl_xor(s1, off, 64);
        int  bi1 = __shfl_xor(i1, off, 64);
        float b2 = __shfl_xor(s2, off, 64);
        int  bi2 = __shfl_xor(i2, off, 64);
        if (b1 < s1) { s2 = s1; i2 = i1; s1 = b1; i1 = bi1; }
        else if (b1 < s2) { s2 = b1; i2 = bi1; }
        if (b2 < s2) { s2 = b2; i2 = bi2; }
    }
    // all lanes converge to the same top-2
    const int yr = yb[row];
    const float sr = sqn[row];
    float w1 = ((yr == yb[i1]) ? 1.f : -1.f) * expf(-sqrtf(fmaxf(sr + s1, 0.f)));
    float w2 = ((yr == yb[i2]) ? 1.f : -1.f) * expf(-sqrtf(fmaxf(sr + s2, 0.f)));

    const float4* yr4 = reinterpret_cast<const float4*>(yo + (size_t)row * ncls);
    const float4* y14 = reinterpret_cast<const float4*>(yo + (size_t)i1 * ncls);
    const float4* y24 = reinterpret_cast<const float4*>(yo + (size_t)i2 * ncls);
    const int nv4 = ncls >> 2;             // 250
    float a1 = 0.f, a2 = 0.f;
    for (int c = lane; c < nv4; c += 64) {
        float4 v = yr4[c];
        float4 u1 = y14[c];
        float4 u2 = y24[c];
        float tx = v.x - u1.x, ty = v.y - u1.y, tz = v.z - u1.z, tw = v.w - u1.w;
        a1 = fmaf(tx, tx, fmaf(ty, ty, fmaf(tz, tz, fmaf(tw, tw, a1))));
        tx = v.x - u2.x; ty = v.y - u2.y; tz = v.z - u2.z; tw = v.w - u2.w;
        a2 = fmaf(tx, tx, fmaf(ty, ty, fmaf(tz, tz, fmaf(tw, tw, a2))));
    }
    for (int c = (nv4 << 2) + lane; c < ncls; c += 64) {   // tail (empty for 1000)
        float v = yo[(size_t)row * ncls + c];
        float t1 = v - yo[(size_t)i1 * ncls + c];
        float t2 = v - yo[(size_t)i2 * ncls + c];
        a1 = fmaf(t1, t1, a1);
        a2 = fmaf(t2, t2, a2);
    }
    for (int off = 1; off < 64; off <<= 1) {
        a1 += __shfl_xor(a1, off, 64);
        a2 += __shfl_xor(a2, off, 64);
    }
    if (lane == 0)
        partial[row] = w1 * sqrtf(a1) + w2 * sqrtf(a2);
}

// ---------------- Kernel D: final reduction of n partials ----------------
__global__ __launch_bounds__(256)
void final_reduce_kernel(const float* __restrict__ partial, float* __restrict__ out, int n) {
    const int t = threadIdx.x;
    __shared__ float red[4];
    float s = 0.f;
    const int nv4 = n >> 2;
    const float4* p4 = reinterpret_cast<const float4*>(partial);
    for (int c = t; c < nv4; c += 256) {
        float4 v = p4[c];
        s += v.x + v.y + v.z + v.w;
    }
    for (int off = 1; off < 64; off <<= 1) s += __shfl_xor(s, off, 64);
    if ((t & 63) == 0) red[t >> 6] = s;
    __syncthreads();
    if (t == 0) out[0] = ALPHA * (red[0] + red[1] + red[2] + red[3]);
}

extern "C" void kernel_launch(void* const* d_in, const int* in_sizes, int n_in,
                              void* d_out, int out_size, void* d_ws, size_t ws_size,
                              hipStream_t stream) {
    const float* X  = (const float*)d_in[0];
    const int*   yb = (const int*)d_in[1];
    const float* yo = (const float*)d_in[2];
    float* out = (float*)d_out;

    const int n    = in_sizes[1];          // 4096
    const int d    = in_sizes[0] / n;      // 1024
    const int ncls = in_sizes[2] / n;      // 1000
    const int nb   = n / BM;               // 32 row/col blocks; 64 strips

    // workspace: sqn | Xb (bf16) | cand_s | cand_i | partial
    char* wsb = (char*)d_ws;
    size_t off = 0;
    float* sqn = (float*)(wsb + off);    off += ((size_t)n * 4 + 255) & ~(size_t)255;
    short* Xb  = (short*)(wsb + off);    off += ((size_t)n * d * 2 + 255) & ~(size_t)255;
    float* cand_s = (float*)(wsb + off); off += ((size_t)n * 64 * 2 * 4 + 255) & ~(size_t)255;
    int*   cand_i = (int*)(wsb + off);   off += ((size_t)n * 64 * 2 * 4 + 255) & ~(size_t)255;
    float* partial = (float*)(wsb + off);

    conv_rownorm_kernel<<<n / 4, 256, 0, stream>>>(X, Xb, sqn, d);

    const int ntri = nb * (nb + 1) / 2;    // 528
    gram_top2_mfma<<<ntri, 256, 0, stream>>>(Xb, sqn, cand_s, cand_i, n, d, nb);

    merge_edges_kernel<<<n / 4, 256, 0, stream>>>(sqn, cand_s, cand_i, yb, yo, partial, ncls);

    final_reduce_kernel<<<1, 256, 0, stream>>>(partial, out, n);
}

// Round 5
// 60.674 us; speedup vs baseline: 7.7691x; 1.0022x over previous
//
#include <hip/hip_runtime.h>
#include <math.h>

#define ALPHA 5e-4f
#define BIG 1e30f

typedef __attribute__((ext_vector_type(8))) short bf16x8;
typedef __attribute__((ext_vector_type(4))) float f32x4;

__device__ __forceinline__ unsigned short f2bf(float x) {
    unsigned u = __builtin_bit_cast(unsigned, x);
    unsigned r = (u + 0x7FFFu + ((u >> 16) & 1u)) >> 16;
    return (unsigned short)r;
}
__device__ __forceinline__ float bf2f(unsigned short b) {
    unsigned u = ((unsigned)b) << 16;
    return __builtin_bit_cast(float, u);
}

__device__ __forceinline__ void gload16(const short* g, short* l) {
    __builtin_amdgcn_global_load_lds(
        (const __attribute__((address_space(1))) void*)g,
        (__attribute__((address_space(3))) void*)l, 16, 0, 0);
}

// ---------------- Kernel A: f32 -> bf16 convert + row squared norms ----------------
__global__ __launch_bounds__(256)
void conv_rownorm_kernel(const float* __restrict__ X, short* __restrict__ Xb,
                         float* __restrict__ sqn, int d) {
    const int w = threadIdx.x >> 6, lane = threadIdx.x & 63;
    const int row = blockIdx.x * 4 + w;
    const float4* src = reinterpret_cast<const float4*>(X + (size_t)row * d);
    short4* dst = reinterpret_cast<short4*>(Xb + (size_t)row * d);
    float s = 0.f;
    const int nv = d >> 2;
    for (int c = lane; c < nv; c += 64) {
        float4 v = src[c];
        unsigned short b0 = f2bf(v.x), b1 = f2bf(v.y), b2 = f2bf(v.z), b3 = f2bf(v.w);
        float x0 = bf2f(b0), x1 = bf2f(b1), x2 = bf2f(b2), x3 = bf2f(b3);
        s += x0 * x0 + x1 * x1 + x2 * x2 + x3 * x3;
        dst[c] = make_short4((short)b0, (short)b1, (short)b2, (short)b3);
    }
    for (int off = 1; off < 64; off <<= 1) s += __shfl_xor(s, off, 64);
    if (lane == 0) sqn[row] = s;
}

// ---------------- Kernel B: bf16 MFMA gram, upper triangle, fused top-2 ----------------
// 128x128 tile, BK=32, 4 waves (2x2).  3-stage LDS ring + counted vmcnt (T3/T4):
// per iter issue stage t+2's loads, wait vmcnt(8) (= stage t landed, 8 newer in
// flight), raw barrier, ds_read+MFMA, lgkmcnt(0), raw barrier.  Never vmcnt(0)
// in the main loop.  LDS swizzle (T2 both-sides) as in R4: slot (row, chunk c)
// holds global chunk c ^ ((row>>1)&3); reads at chunk lg ^ ((lc>>1)&3).
#define BM 128
#define BN 128
#define BK 32

__global__ __launch_bounds__(256)
void gram_top2_mfma(const short* __restrict__ Xb, const float* __restrict__ sqn,
                    float* __restrict__ cand_s, int* __restrict__ cand_i,
                    int n, int d, int nb, int cpx) {
    __shared__ short As[3][BM * BK];
    __shared__ short Bs[3][BN * BK];

    // T1: XCD-aware bijective swizzle (nwg % 8 == 0), then triangular decode
    const int nwg = nb * (nb + 1) / 2;
    int bid = blockIdx.x;
    int swz = (bid & 7) * cpx + (bid >> 3);
    (void)nwg;
    int rb = 0, rem = swz;
    while (rem >= nb - rb) { rem -= nb - rb; ++rb; }
    const int cb = rb + rem;

    const int row0 = rb * BM, col0 = cb * BN;
    const int t = threadIdx.x;
    const int w = t >> 6, l = t & 63;
    const int wr = w >> 1, wc = w & 1;
    const int lc = l & 15, lg = l >> 4;

    f32x4 acc[4][4];
#pragma unroll
    for (int i = 0; i < 4; ++i)
#pragma unroll
        for (int j = 0; j < 4; ++j) acc[i][j] = (f32x4){0.f, 0.f, 0.f, 0.f};

    const int gchunk = (t & 3) ^ ((t >> 3) & 3);
    const size_t gA0 = (size_t)(row0 + (t >> 2)) * d + gchunk * 8;
    const size_t gB0 = (size_t)(col0 + (t >> 2)) * d + gchunk * 8;
    const size_t rstep = (size_t)64 * d;
    const int kswz = (lg ^ ((lc >> 1) & 3)) * 8;
    const int wbase = w * 512;

    const int nsteps = d / BK;             // 32

    // prologue: stage 0 -> ring0, stage 1 -> ring1
    {
        short* la = As[0] + wbase;  short* lb = Bs[0] + wbase;
        gload16(Xb + gA0, la);          gload16(Xb + gA0 + rstep, la + 2048);
        gload16(Xb + gB0, lb);          gload16(Xb + gB0 + rstep, lb + 2048);
        la = As[1] + wbase;  lb = Bs[1] + wbase;
        gload16(Xb + gA0 + BK, la);     gload16(Xb + gA0 + BK + rstep, la + 2048);
        gload16(Xb + gB0 + BK, lb);     gload16(Xb + gB0 + BK + rstep, lb + 2048);
    }

    int s0 = 0, s1 = 1, s2 = 2;            // ring indices: read s0, issue into s2
    for (int ks = 0; ks < nsteps; ++ks) {
        if (ks + 2 < nsteps) {
            short* la = As[s2] + wbase;  short* lb = Bs[s2] + wbase;
            const size_t ko = (size_t)(ks + 2) * BK;
            gload16(Xb + gA0 + ko, la);      gload16(Xb + gA0 + ko + rstep, la + 2048);
            gload16(Xb + gB0 + ko, lb);      gload16(Xb + gB0 + ko + rstep, lb + 2048);
            asm volatile("s_waitcnt vmcnt(8)" ::: "memory");
        } else if (ks + 1 < nsteps) {
            asm volatile("s_waitcnt vmcnt(4)" ::: "memory");
        } else {
            asm volatile("s_waitcnt vmcnt(0)" ::: "memory");
        }
        __builtin_amdgcn_s_barrier();      // stage ks visible to all waves

        bf16x8 a[4], b[4];
#pragma unroll
        for (int mi = 0; mi < 4; ++mi)
            a[mi] = *reinterpret_cast<const bf16x8*>(&As[s0][(wr * 64 + mi * 16 + lc) * BK + kswz]);
#pragma unroll
        for (int ni = 0; ni < 4; ++ni)
            b[ni] = *reinterpret_cast<const bf16x8*>(&Bs[s0][(wc * 64 + ni * 16 + lc) * BK + kswz]);
#pragma unroll
        for (int mi = 0; mi < 4; ++mi)
#pragma unroll
            for (int ni = 0; ni < 4; ++ni)
                acc[mi][ni] = __builtin_amdgcn_mfma_f32_16x16x32_bf16(
                    a[mi], b[ni], acc[mi][ni], 0, 0, 0);

        asm volatile("s_waitcnt lgkmcnt(0)" ::: "memory");
        __builtin_amdgcn_s_barrier();      // all reads of s0 done -> s0 reusable
        int tmp = s0; s0 = s1; s1 = s2; s2 = tmp;
    }

    // ---- row-path epilogue: per-row top-2 over this wave's 64-col strip ----
    // C frag layout: col = lane&15, row = (lane>>4)*4 + reg.
    float sq_c[4];
#pragma unroll
    for (int ni = 0; ni < 4; ++ni) sq_c[ni] = sqn[col0 + wc * 64 + ni * 16 + lc];
    const int strip_r = cb * 2 + wc;

#pragma unroll
    for (int mi = 0; mi < 4; ++mi) {
#pragma unroll
        for (int j = 0; j < 4; ++j) {
            const int grow = row0 + wr * 64 + mi * 16 + lg * 4 + j;
            float s1v = BIG, s2v = BIG;
            int i1 = -1, i2 = -1;
#pragma unroll
            for (int ni = 0; ni < 4; ++ni) {
                const int gcol = col0 + wc * 64 + ni * 16 + lc;
                float s = sq_c[ni] - 2.f * acc[mi][ni][j];
                if (gcol == grow) s = BIG;   // exclude self (diag blocks)
                if (s < s1v) { s2v = s1v; i2 = i1; s1v = s; i1 = gcol; }
                else if (s < s2v) { s2v = s; i2 = gcol; }
            }
            for (int off = 1; off < 16; off <<= 1) {
                float b1 = __shfl_xor(s1v, off, 16);
                int  bi1 = __shfl_xor(i1, off, 16);
                float b2 = __shfl_xor(s2v, off, 16);
                int  bi2 = __shfl_xor(i2, off, 16);
                if (b1 < s1v) { s2v = s1v; i2 = i1; s1v = b1; i1 = bi1; }
                else if (b1 < s2v) { s2v = b1; i2 = bi1; }
                if (b2 < s2v) { s2v = b2; i2 = bi2; }
            }
            if (lc == 0) {
                size_t base = ((size_t)grow * 64 + strip_r) * 2;
                cand_s[base] = s1v; cand_s[base + 1] = s2v;
                cand_i[base] = i1; cand_i[base + 1] = i2;
            }
        }
    }

    // ---- col-path epilogue (off-diagonal blocks): per-col top-2 over 64 rows ----
    if (rb != cb) {
        float sq_r[4][4];
#pragma unroll
        for (int mi = 0; mi < 4; ++mi)
#pragma unroll
            for (int j = 0; j < 4; ++j)
                sq_r[mi][j] = sqn[row0 + wr * 64 + mi * 16 + lg * 4 + j];
        const int strip_c = rb * 2 + wr;

#pragma unroll
        for (int ni = 0; ni < 4; ++ni) {
            const int gcol = col0 + wc * 64 + ni * 16 + lc;
            float s1v = BIG, s2v = BIG;
            int i1 = -1, i2 = -1;
#pragma unroll
            for (int mi = 0; mi < 4; ++mi)
#pragma unroll
                for (int j = 0; j < 4; ++j) {
                    const int grow = row0 + wr * 64 + mi * 16 + lg * 4 + j;
                    float s = sq_r[mi][j] - 2.f * acc[mi][ni][j];
                    if (s < s1v) { s2v = s1v; i2 = i1; s1v = s; i1 = grow; }
                    else if (s < s2v) { s2v = s; i2 = grow; }
                }
#pragma unroll
            for (int off = 16; off < 64; off <<= 1) {
                float b1 = __shfl_xor(s1v, off, 64);
                int  bi1 = __shfl_xor(i1, off, 64);
                float b2 = __shfl_xor(s2v, off, 64);
                int  bi2 = __shfl_xor(i2, off, 64);
                if (b1 < s1v) { s2v = s1v; i2 = i1; s1v = b1; i1 = bi1; }
                else if (b1 < s2v) { s2v = b1; i2 = bi1; }
                if (b2 < s2v) { s2v = b2; i2 = bi2; }
            }
            if (lg == 0) {
                size_t base = ((size_t)gcol * 64 + strip_c) * 2;
                cand_s[base] = s1v; cand_s[base + 1] = s2v;
                cand_i[base] = i1; cand_i[base + 1] = i2;
            }
        }
    }
}

// ---------------- Kernel C: merge 128 candidates/row + edge terms ----------------
__global__ __launch_bounds__(256)
void merge_edges_kernel(const float* __restrict__ sqn,
                        const float* __restrict__ cand_s, const int* __restrict__ cand_i,
                        const int* __restrict__ yb, const float* __restrict__ yo,
                        float* __restrict__ partial, int ncls) {
    const int w = threadIdx.x >> 6, lane = threadIdx.x & 63;
    const int row = blockIdx.x * 4 + w;

    float2 cs = reinterpret_cast<const float2*>(cand_s + (size_t)row * 128)[lane];
    int2   ci = reinterpret_cast<const int2*>(cand_i + (size_t)row * 128)[lane];
    float s1 = cs.x, s2 = cs.y;
    int i1 = ci.x, i2 = ci.y;
    if (s2 < s1) { float ts = s1; s1 = s2; s2 = ts; int ti = i1; i1 = i2; i2 = ti; }

    for (int off = 1; off < 64; off <<= 1) {
        float b1 = __shfl_xor(s1, off, 64);
        int  bi1 = __shfl_xor(i1, off, 64);
        float b2 = __shfl_xor(s2, off, 64);
        int  bi2 = __shfl_xor(i2, off, 64);
        if (b1 < s1) { s2 = s1; i2 = i1; s1 = b1; i1 = bi1; }
        else if (b1 < s2) { s2 = b1; i2 = bi1; }
        if (b2 < s2) { s2 = b2; i2 = bi2; }
    }
    const int yr = yb[row];
    const float sr = sqn[row];
    float w1 = ((yr == yb[i1]) ? 1.f : -1.f) * expf(-sqrtf(fmaxf(sr + s1, 0.f)));
    float w2 = ((yr == yb[i2]) ? 1.f : -1.f) * expf(-sqrtf(fmaxf(sr + s2, 0.f)));

    const float4* yr4 = reinterpret_cast<const float4*>(yo + (size_t)row * ncls);
    const float4* y14 = reinterpret_cast<const float4*>(yo + (size_t)i1 * ncls);
    const float4* y24 = reinterpret_cast<const float4*>(yo + (size_t)i2 * ncls);
    const int nv4 = ncls >> 2;             // 250
    float a1 = 0.f, a2 = 0.f;
    for (int c = lane; c < nv4; c += 64) {
        float4 v = yr4[c];
        float4 u1 = y14[c];
        float4 u2 = y24[c];
        float tx = v.x - u1.x, ty = v.y - u1.y, tz = v.z - u1.z, tw = v.w - u1.w;
        a1 = fmaf(tx, tx, fmaf(ty, ty, fmaf(tz, tz, fmaf(tw, tw, a1))));
        tx = v.x - u2.x; ty = v.y - u2.y; tz = v.z - u2.z; tw = v.w - u2.w;
        a2 = fmaf(tx, tx, fmaf(ty, ty, fmaf(tz, tz, fmaf(tw, tw, a2))));
    }
    for (int c = (nv4 << 2) + lane; c < ncls; c += 64) {   // tail (empty for 1000)
        float v = yo[(size_t)row * ncls + c];
        float t1 = v - yo[(size_t)i1 * ncls + c];
        float t2 = v - yo[(size_t)i2 * ncls + c];
        a1 = fmaf(t1, t1, a1);
        a2 = fmaf(t2, t2, a2);
    }
    for (int off = 1; off < 64; off <<= 1) {
        a1 += __shfl_xor(a1, off, 64);
        a2 += __shfl_xor(a2, off, 64);
    }
    if (lane == 0)
        partial[row] = w1 * sqrtf(a1) + w2 * sqrtf(a2);
}

// ---------------- Kernel D: final reduction of n partials ----------------
__global__ __launch_bounds__(256)
void final_reduce_kernel(const float* __restrict__ partial, float* __restrict__ out, int n) {
    const int t = threadIdx.x;
    __shared__ float red[4];
    float s = 0.f;
    const int nv4 = n >> 2;
    const float4* p4 = reinterpret_cast<const float4*>(partial);
    for (int c = t; c < nv4; c += 256) {
        float4 v = p4[c];
        s += v.x + v.y + v.z + v.w;
    }
    for (int off = 1; off < 64; off <<= 1) s += __shfl_xor(s, off, 64);
    if ((t & 63) == 0) red[t >> 6] = s;
    __syncthreads();
    if (t == 0) out[0] = ALPHA * (red[0] + red[1] + red[2] + red[3]);
}

extern "C" void kernel_launch(void* const* d_in, const int* in_sizes, int n_in,
                              void* d_out, int out_size, void* d_ws, size_t ws_size,
                              hipStream_t stream) {
    const float* X  = (const float*)d_in[0];
    const int*   yb = (const int*)d_in[1];
    const float* yo = (const float*)d_in[2];
    float* out = (float*)d_out;

    const int n    = in_sizes[1];          // 4096
    const int d    = in_sizes[0] / n;      // 1024
    const int ncls = in_sizes[2] / n;      // 1000
    const int nb   = n / BM;               // 32 row/col blocks; 64 strips

    // workspace: sqn | Xb (bf16) | cand_s | cand_i | partial
    char* wsb = (char*)d_ws;
    size_t off = 0;
    float* sqn = (float*)(wsb + off);    off += ((size_t)n * 4 + 255) & ~(size_t)255;
    short* Xb  = (short*)(wsb + off);    off += ((size_t)n * d * 2 + 255) & ~(size_t)255;
    float* cand_s = (float*)(wsb + off); off += ((size_t)n * 64 * 2 * 4 + 255) & ~(size_t)255;
    int*   cand_i = (int*)(wsb + off);   off += ((size_t)n * 64 * 2 * 4 + 255) & ~(size_t)255;
    float* partial = (float*)(wsb + off);

    conv_rownorm_kernel<<<n / 4, 256, 0, stream>>>(X, Xb, sqn, d);

    const int ntri = nb * (nb + 1) / 2;    // 528 (divisible by 8)
    const int cpx  = ntri / 8;             // 66 blocks per XCD chunk
    gram_top2_mfma<<<ntri, 256, 0, stream>>>(Xb, sqn, cand_s, cand_i, n, d, nb, cpx);

    merge_edges_kernel<<<n / 4, 256, 0, stream>>>(sqn, cand_s, cand_i, yb, yo, partial, ncls);

    final_reduce_kernel<<<1, 256, 0, stream>>>(partial, out, n);
}